// Round 1
// baseline (346.825 us; speedup 1.0000x reference)
//
#include <hip/hip_runtime.h>

#define E_N 30000
#define KDIM 1024
#define E_DIRN 65536
#define E_UNDN 65536
#define E_EKN 120000
#define NB (1024 + 1024 + E_N)            // 32048 bins: dir rows, und rows, ek rows
#define TOT_E (E_DIRN + E_UNDN + E_EKN)   // 251072

// ---------------- GEMM: Z_l = kn_emb @ W_l for l in {dir, und, ek} ----------------
__global__ __launch_bounds__(256) void gemm_z(
    const float* __restrict__ A, const float* __restrict__ W0,
    const float* __restrict__ W1, const float* __restrict__ W2,
    float* __restrict__ Zall)
{
    const float* B = (blockIdx.z == 0) ? W0 : (blockIdx.z == 1) ? W1 : W2;
    float* C = Zall + (size_t)blockIdx.z * KDIM * KDIM;
    __shared__ float As[16][68];   // A tile transposed: As[k][m], rows 272B (16B aligned)
    __shared__ float Bs[16][68];   // Bs[k][n]
    int tid = threadIdx.x;
    int tx = tid & 15, ty = tid >> 4;
    int tm = blockIdx.x * 64, tn = blockIdx.y * 64;
    float acc[4][4] = {};
    for (int kk = 0; kk < KDIM; kk += 16) {
        {
            int r = tid >> 2, kc = (tid & 3) * 4;
            float4 a4 = *(const float4*)&A[(size_t)(tm + r) * KDIM + kk + kc];
            As[kc + 0][r] = a4.x; As[kc + 1][r] = a4.y;
            As[kc + 2][r] = a4.z; As[kc + 3][r] = a4.w;
        }
        {
            int kr = tid >> 4, c = (tid & 15) * 4;
            float4 b4 = *(const float4*)&B[(size_t)(kk + kr) * KDIM + tn + c];
            *(float4*)&Bs[kr][c] = b4;
        }
        __syncthreads();
#pragma unroll
        for (int k = 0; k < 16; ++k) {
            float4 av = *(const float4*)&As[k][ty * 4];
            float4 bv = *(const float4*)&Bs[k][tx * 4];
            acc[0][0] += av.x * bv.x; acc[0][1] += av.x * bv.y; acc[0][2] += av.x * bv.z; acc[0][3] += av.x * bv.w;
            acc[1][0] += av.y * bv.x; acc[1][1] += av.y * bv.y; acc[1][2] += av.y * bv.z; acc[1][3] += av.y * bv.w;
            acc[2][0] += av.z * bv.x; acc[2][1] += av.z * bv.y; acc[2][2] += av.z * bv.z; acc[2][3] += av.z * bv.w;
            acc[3][0] += av.w * bv.x; acc[3][1] += av.w * bv.y; acc[3][2] += av.w * bv.z; acc[3][3] += av.w * bv.w;
        }
        __syncthreads();
    }
#pragma unroll
    for (int i = 0; i < 4; ++i) {
        float4 v = make_float4(acc[i][0], acc[i][1], acc[i][2], acc[i][3]);
        *(float4*)&C[(size_t)(tm + ty * 4 + i) * KDIM + tn + tx * 4] = v;
    }
}

// ---------------- zs_l = Z_l @ a_l[:K] (source scores; dst scores cancel in softmax) --
__global__ __launch_bounds__(256) void rowdot(
    const float* __restrict__ Zall, const float* __restrict__ a_dir,
    const float* __restrict__ a_und, const float* __restrict__ a_ek,
    float* __restrict__ zs)
{
    int l = blockIdx.y;
    const float* M = Zall + (size_t)l * KDIM * KDIM;
    const float* a = (l == 0) ? a_dir : (l == 1) ? a_und : a_ek;
    int row = blockIdx.x, tid = threadIdx.x;
    float4 m4 = *(const float4*)&M[(size_t)row * KDIM + tid * 4];
    float4 a4 = *(const float4*)&a[tid * 4];
    float p = m4.x * a4.x + m4.y * a4.y + m4.z * a4.z + m4.w * a4.w;
    __shared__ float red[256];
    red[tid] = p; __syncthreads();
    for (int s = 128; s > 0; s >>= 1) { if (tid < s) red[tid] += red[tid + s]; __syncthreads(); }
    if (tid == 0) zs[l * KDIM + row] = red[0];
}

// ---------------- CSR build: count -> scan -> scatter ----------------
__global__ __launch_bounds__(256) void count_edges(
    const int* __restrict__ dir_dst, const int* __restrict__ und_dst,
    const int* __restrict__ ek_dst, int* __restrict__ counts)
{
    int i = blockIdx.x * 256 + threadIdx.x;
    if (i < E_DIRN) atomicAdd(&counts[dir_dst[i]], 1);
    else if (i < E_DIRN + E_UNDN) atomicAdd(&counts[1024 + und_dst[i - E_DIRN]], 1);
    else if (i < TOT_E) atomicAdd(&counts[2048 + ek_dst[i - E_DIRN - E_UNDN]], 1);
}

__global__ __launch_bounds__(1024) void scan_bins(
    const int* __restrict__ counts, int* __restrict__ offsets)
{
    __shared__ int sums[1024];
    int tid = threadIdx.x;
    const int C = (NB + 1023) / 1024;  // 32
    int base = tid * C;
    int s = 0;
    for (int j = 0; j < C; ++j) { int idx = base + j; if (idx < NB) s += counts[idx]; }
    sums[tid] = s; __syncthreads();
    for (int off = 1; off < 1024; off <<= 1) {
        int v = (tid >= off) ? sums[tid - off] : 0;
        __syncthreads();
        sums[tid] += v;
        __syncthreads();
    }
    int run = (tid == 0) ? 0 : sums[tid - 1];
    for (int j = 0; j < C; ++j) {
        int idx = base + j;
        if (idx < NB) { offsets[idx] = run; run += counts[idx]; }
    }
}

__global__ __launch_bounds__(256) void scatter_edges(
    const int* __restrict__ dir_dst, const int* __restrict__ und_dst,
    const int* __restrict__ ek_dst, const int* __restrict__ offsets,
    int* __restrict__ cursor, int* __restrict__ edge_idx)
{
    int i = blockIdx.x * 256 + threadIdx.x;
    int bin, loc;
    if (i < E_DIRN) { bin = dir_dst[i]; loc = i; }
    else if (i < E_DIRN + E_UNDN) { loc = i - E_DIRN; bin = 1024 + und_dst[loc]; }
    else if (i < TOT_E) { loc = i - E_DIRN - E_UNDN; bin = 2048 + ek_dst[loc]; }
    else return;
    int pos = offsets[bin] + atomicAdd(&cursor[bin], 1);
    edge_idx[pos] = loc;
}

// ---------------- k_directed / k_undirected rows (softmax + weighted sum) ------------
__global__ __launch_bounds__(256) void gat_kn(
    const float* __restrict__ Zall, const float* __restrict__ zs,
    const int* __restrict__ dir_src, const int* __restrict__ und_src,
    const int* __restrict__ offsets, const int* __restrict__ counts,
    const int* __restrict__ edge_idx,
    float* __restrict__ Bk, float* __restrict__ Ck)
{
    int bin = blockIdx.x;
    int g = bin >> 10, row = bin & 1023;
    const int* srcA = g ? und_src : dir_src;
    const float* Z = Zall + (size_t)g * KDIM * KDIM;
    const float* zsv = zs + g * KDIM;
    float* out = g ? Ck : Bk;
    int tid = threadIdx.x;
    int start = offsets[bin], n = counts[bin];
    __shared__ float red[256];
    __shared__ float exs[256];
    __shared__ int   srcs[256];
    float p = 0.f;
    for (int j = tid; j < n; j += 256) {
        int e = edge_idx[start + j];
        p += expf(zsv[srcA[e]]);
    }
    red[tid] = p; __syncthreads();
    for (int s = 128; s > 0; s >>= 1) { if (tid < s) red[tid] += red[tid + s]; __syncthreads(); }
    float inv_den = (n > 0) ? 1.f / red[0] : 0.f;
    float4 acc = make_float4(0.f, 0.f, 0.f, 0.f);
    for (int c0 = 0; c0 < n; c0 += 256) {
        int m = min(256, n - c0);
        __syncthreads();
        if (tid < m) {
            int e = edge_idx[start + c0 + tid];
            int s = srcA[e];
            srcs[tid] = s;
            exs[tid] = expf(zsv[s]) * inv_den;
        }
        __syncthreads();
        for (int j = 0; j < m; ++j) {
            float al = exs[j];
            float4 z4 = *(const float4*)&Z[(size_t)srcs[j] * KDIM + tid * 4];
            acc.x += al * z4.x; acc.y += al * z4.y; acc.z += al * z4.z; acc.w += al * z4.w;
        }
    }
    *(float4*)&out[(size_t)row * KDIM + tid * 4] = acc;
}

// ---------------- exer_out rows: Be accumulation + se dot + final write (fused) ------
__global__ __launch_bounds__(256) void exer_rows(
    const float* __restrict__ exer, const float* __restrict__ Zek,
    const float* __restrict__ zs_ek, const int* __restrict__ ek_src,
    const int* __restrict__ offsets, const int* __restrict__ counts,
    const int* __restrict__ edge_idx,
    const float* __restrict__ e_w1, const float* __restrict__ e_b1,
    float* __restrict__ out)
{
    int row = blockIdx.x, tid = threadIdx.x;
    int bin = 2048 + row;
    int start = offsets[bin], n = counts[bin];
    float4 x4 = *(const float4*)&exer[(size_t)row * KDIM + tid * 4];
    float den = 0.f;
    for (int j = 0; j < n; ++j) {
        int e = edge_idx[start + j];
        den += expf(zs_ek[ek_src[e] - E_N]);
    }
    float inv = (n > 0) ? 1.f / den : 0.f;
    float4 be = make_float4(0.f, 0.f, 0.f, 0.f);
    for (int j = 0; j < n; ++j) {
        int e = edge_idx[start + j];
        int s = ek_src[e] - E_N;
        float al = expf(zs_ek[s]) * inv;
        float4 z4 = *(const float4*)&Zek[(size_t)s * KDIM + tid * 4];
        be.x += al * z4.x; be.y += al * z4.y; be.z += al * z4.z; be.w += al * z4.w;
    }
    float4 wa = *(const float4*)&e_w1[tid * 4];
    float4 wb = *(const float4*)&e_w1[KDIM + tid * 4];
    float p = x4.x * wa.x + x4.y * wa.y + x4.z * wa.z + x4.w * wa.w
            + be.x * wb.x + be.y * wb.y + be.z * wb.z + be.w * wb.w;
    __shared__ float red[256];
    red[tid] = p; __syncthreads();
    for (int s = 128; s > 0; s >>= 1) { if (tid < s) red[tid] += red[tid + s]; __syncthreads(); }
    float se = red[0] + e_b1[0];
    float4 o;
    o.x = x4.x + se * be.x; o.y = x4.y + se * be.y;
    o.z = x4.z + se * be.z; o.w = x4.w + se * be.w;
    *(float4*)&out[(size_t)row * KDIM + tid * 4] = o;
}

// ---------------- kn_out rows: 2-way gated combine ----------------
__global__ __launch_bounds__(256) void kn_rows(
    const float* __restrict__ A, const float* __restrict__ Bk, const float* __restrict__ Ck,
    const float* __restrict__ k_w1, const float* __restrict__ k_b1,
    const float* __restrict__ k_w2, const float* __restrict__ k_b2,
    float* __restrict__ out)
{
    int row = blockIdx.x, tid = threadIdx.x;
    float4 a4 = *(const float4*)&A[(size_t)row * KDIM + tid * 4];
    float4 b4 = *(const float4*)&Bk[(size_t)row * KDIM + tid * 4];
    float4 c4 = *(const float4*)&Ck[(size_t)row * KDIM + tid * 4];
    float4 w1a = *(const float4*)&k_w1[tid * 4];
    float4 w1b = *(const float4*)&k_w1[KDIM + tid * 4];
    float4 w2a = *(const float4*)&k_w2[tid * 4];
    float4 w2b = *(const float4*)&k_w2[KDIM + tid * 4];
    float p1 = a4.x * w1a.x + a4.y * w1a.y + a4.z * w1a.z + a4.w * w1a.w
             + b4.x * w1b.x + b4.y * w1b.y + b4.z * w1b.z + b4.w * w1b.w;
    float p2 = a4.x * w2a.x + a4.y * w2a.y + a4.z * w2a.z + a4.w * w2a.w
             + c4.x * w2b.x + c4.y * w2b.y + c4.z * w2b.z + c4.w * w2b.w;
    __shared__ float r1[256];
    __shared__ float r2[256];
    r1[tid] = p1; r2[tid] = p2; __syncthreads();
    for (int s = 128; s > 0; s >>= 1) {
        if (tid < s) { r1[tid] += r1[tid + s]; r2[tid] += r2[tid + s]; }
        __syncthreads();
    }
    float s1 = r1[0] + k_b1[0];
    float s2 = r2[0] + k_b2[0];
    float m = fmaxf(s1, s2);
    float e1 = expf(s1 - m), e2 = expf(s2 - m);
    float isum = 1.f / (e1 + e2);
    float sc0 = e1 * isum, sc1 = e2 * isum;
    float4 o;
    o.x = a4.x + sc0 * b4.x + sc1 * c4.x;
    o.y = a4.y + sc0 * b4.y + sc1 * c4.y;
    o.z = a4.z + sc0 * b4.z + sc1 * c4.z;
    o.w = a4.w + sc0 * b4.w + sc1 * c4.w;
    *(float4*)&out[(size_t)row * KDIM + tid * 4] = o;
}

extern "C" void kernel_launch(void* const* d_in, const int* in_sizes, int n_in,
                              void* d_out, int out_size, void* d_ws, size_t ws_size,
                              hipStream_t stream)
{
    (void)in_sizes; (void)n_in; (void)out_size; (void)ws_size;
    const float* exer  = (const float*)d_in[0];
    const float* kn    = (const float*)d_in[1];
    const int* dir_src = (const int*)d_in[2];
    const int* dir_dst = (const int*)d_in[3];
    const int* und_src = (const int*)d_in[4];
    const int* und_dst = (const int*)d_in[5];
    const int* ek_src  = (const int*)d_in[6];
    const int* ek_dst  = (const int*)d_in[7];
    const float* W_dir = (const float*)d_in[8];
    const float* a_dir = (const float*)d_in[9];
    const float* W_und = (const float*)d_in[10];
    const float* a_und = (const float*)d_in[11];
    const float* W_ek  = (const float*)d_in[12];
    const float* a_ek  = (const float*)d_in[13];
    const float* k_w1  = (const float*)d_in[14];
    const float* k_b1  = (const float*)d_in[15];
    const float* k_w2  = (const float*)d_in[16];
    const float* k_b2  = (const float*)d_in[17];
    const float* e_w1  = (const float*)d_in[18];
    const float* e_b1  = (const float*)d_in[19];

    char* ws = (char*)d_ws;
    float* Zall    = (float*)ws; ws += (size_t)3 * KDIM * KDIM * 4;
    float* Bk      = (float*)ws; ws += (size_t)KDIM * KDIM * 4;
    float* Ck      = (float*)ws; ws += (size_t)KDIM * KDIM * 4;
    float* zs      = (float*)ws; ws += 3 * KDIM * 4;
    int* counts    = (int*)ws;   ws += NB * 4;
    int* cursor    = (int*)ws;   ws += NB * 4;   // contiguous with counts for one memset
    int* offsets   = (int*)ws;   ws += NB * 4;
    int* edge_idx  = (int*)ws;   ws += (size_t)TOT_E * 4;

    hipMemsetAsync(counts, 0, (size_t)2 * NB * 4, stream);

    gemm_z<<<dim3(16, 16, 3), 256, 0, stream>>>(kn, W_dir, W_und, W_ek, Zall);
    rowdot<<<dim3(KDIM, 3), 256, 0, stream>>>(Zall, a_dir, a_und, a_ek, zs);

    int eb = (TOT_E + 255) / 256;
    count_edges<<<eb, 256, 0, stream>>>(dir_dst, und_dst, ek_dst, counts);
    scan_bins<<<1, 1024, 0, stream>>>(counts, offsets);
    scatter_edges<<<eb, 256, 0, stream>>>(dir_dst, und_dst, ek_dst, offsets, cursor, edge_idx);

    gat_kn<<<2048, 256, 0, stream>>>(Zall, zs, dir_src, und_src, offsets, counts, edge_idx, Bk, Ck);

    float* out = (float*)d_out;
    exer_rows<<<E_N, 256, 0, stream>>>(exer, Zall + (size_t)2 * KDIM * KDIM, zs + 2 * KDIM,
                                       ek_src, offsets, counts, edge_idx, e_w1, e_b1, out);
    kn_rows<<<KDIM, 256, 0, stream>>>(kn, Bk, Ck, k_w1, k_b1, k_w2, k_b2,
                                      out + (size_t)E_N * KDIM);
}

// Round 2
// 268.664 us; speedup vs baseline: 1.2909x; 1.2909x over previous
//
#include <hip/hip_runtime.h>

#define E_N 30000
#define KDIM 1024
#define E_DIRN 65536
#define E_UNDN 65536
#define E_EKN 120000
#define NB (1024 + 1024 + E_N)            // 32048 bins: dir rows, und rows, ek rows
#define TOT_E (E_DIRN + E_UNDN + E_EKN)   // 251072

typedef __attribute__((ext_vector_type(8))) short bfrag8;
typedef __attribute__((ext_vector_type(4))) float facc4;

static __device__ __forceinline__ unsigned short f2bf(float f) {
    unsigned int u = __float_as_uint(f);
    u += 0x7fffu + ((u >> 16) & 1u);   // RNE (NaN not expected here)
    return (unsigned short)(u >> 16);
}
static __device__ __forceinline__ unsigned int pack2(float lo, float hi) {
    return (unsigned int)f2bf(lo) | ((unsigned int)f2bf(hi) << 16);
}

// ---------------- fp32 -> bf16 convert of kn_emb (row-major) ----------------
__global__ __launch_bounds__(256) void convert_kn(
    const float* __restrict__ in, unsigned short* __restrict__ outb)
{
    int idx = blockIdx.x * 256 + threadIdx.x;          // 8 elements per thread
    const float4 a = *(const float4*)&in[(size_t)idx * 8];
    const float4 b = *(const float4*)&in[(size_t)idx * 8 + 4];
    uint4 o;
    o.x = pack2(a.x, a.y); o.y = pack2(a.z, a.w);
    o.z = pack2(b.x, b.y); o.w = pack2(b.z, b.w);
    *(uint4*)&outb[(size_t)idx * 8] = o;
}

// ---------------- W (K x N) -> Wt bf16 (N x K), 3 matrices ----------------
__global__ __launch_bounds__(256) void transpose_w(
    const float* __restrict__ W0, const float* __restrict__ W1,
    const float* __restrict__ W2, unsigned short* __restrict__ Wtall)
{
    int z = blockIdx.z;
    const float* W = (z == 0) ? W0 : (z == 1) ? W1 : W2;
    unsigned short* Wt = Wtall + (size_t)z * KDIM * KDIM;
    __shared__ float tile[32][33];
    int tx = threadIdx.x, ty = threadIdx.y;            // block (32,8)
    int nb = blockIdx.x * 32, kb = blockIdx.y * 32;
#pragma unroll
    for (int r0 = 0; r0 < 32; r0 += 8)
        tile[r0 + ty][tx] = W[(size_t)(kb + r0 + ty) * KDIM + nb + tx];
    __syncthreads();
#pragma unroll
    for (int r0 = 0; r0 < 32; r0 += 8)
        Wt[(size_t)(nb + r0 + ty) * KDIM + kb + tx] = f2bf(tile[tx][r0 + ty]);
}

// ---------------- MFMA GEMM: Z_l = kn @ W_l (bf16 in, fp32 out) ----------------
// 128x128 tile, BK=64, 4 waves each computing 64x64 (4x4 frags of 16x16x32).
__global__ __launch_bounds__(256) void gemm_mfma(
    const unsigned short* __restrict__ Ab,    // knb [1024][1024] row-major
    const unsigned short* __restrict__ Btall, // Wt  [3][1024][1024] (row=n, col=k)
    float* __restrict__ Zall)
{
    const unsigned short* Bb = Btall + (size_t)blockIdx.z * KDIM * KDIM;
    float* C = Zall + (size_t)blockIdx.z * KDIM * KDIM;
    __shared__ unsigned short As[128 * 64];
    __shared__ unsigned short Bs[128 * 64];
    int tid = threadIdx.x;
    int lane = tid & 63, wv = tid >> 6;
    int wr = wv >> 1, wc = wv & 1;
    int tm = blockIdx.x * 128, tn = blockIdx.y * 128;
    facc4 acc[4][4] = {};
    for (int kk = 0; kk < KDIM; kk += 64) {
#pragma unroll
        for (int i = 0; i < 4; ++i) {
            int u = i * 256 + tid;                 // 16B-chunk id, 1024 chunks per tile
            int row = u >> 3, ch = u & 7;
            bfrag8 av = *(const bfrag8*)&Ab[(size_t)(tm + row) * KDIM + kk + ch * 8];
            bfrag8 bv = *(const bfrag8*)&Bb[(size_t)(tn + row) * KDIM + kk + ch * 8];
            *(bfrag8*)&As[row * 64 + ((ch ^ (row & 7)) << 3)] = av;
            *(bfrag8*)&Bs[row * 64 + ((ch ^ (row & 7)) << 3)] = bv;
        }
        __syncthreads();
#pragma unroll
        for (int ks = 0; ks < 2; ++ks) {
            bfrag8 af[4], bf[4];
            int kch = ks * 4 + (lane >> 4);
#pragma unroll
            for (int f = 0; f < 4; ++f) {
                int ar = wr * 64 + f * 16 + (lane & 15);
                af[f] = *(const bfrag8*)&As[ar * 64 + ((kch ^ (ar & 7)) << 3)];
                int bc = wc * 64 + f * 16 + (lane & 15);
                bf[f] = *(const bfrag8*)&Bs[bc * 64 + ((kch ^ (bc & 7)) << 3)];
            }
#pragma unroll
            for (int i = 0; i < 4; ++i)
#pragma unroll
                for (int j = 0; j < 4; ++j)
                    acc[i][j] = __builtin_amdgcn_mfma_f32_16x16x32_bf16(af[i], bf[j], acc[i][j], 0, 0, 0);
        }
        __syncthreads();
    }
    int col0 = lane & 15, r0 = (lane >> 4) * 4;
#pragma unroll
    for (int i = 0; i < 4; ++i)
#pragma unroll
        for (int j = 0; j < 4; ++j) {
            int row = tm + wr * 64 + i * 16 + r0;
            int col = tn + wc * 64 + j * 16 + col0;
#pragma unroll
            for (int r = 0; r < 4; ++r)
                C[(size_t)(row + r) * KDIM + col] = acc[i][j][r];
        }
}

// ---------------- expzs_l[row] = exp(Z_l[row,:] . a_l[:K]) ----------------
__global__ __launch_bounds__(256) void rowdot_exp(
    const float* __restrict__ Zall, const float* __restrict__ a_dir,
    const float* __restrict__ a_und, const float* __restrict__ a_ek,
    float* __restrict__ expzs)
{
    int l = blockIdx.y;
    const float* M = Zall + (size_t)l * KDIM * KDIM;
    const float* a = (l == 0) ? a_dir : (l == 1) ? a_und : a_ek;
    int row = blockIdx.x, tid = threadIdx.x;
    float4 m4 = *(const float4*)&M[(size_t)row * KDIM + tid * 4];
    float4 a4 = *(const float4*)&a[tid * 4];
    float p = m4.x * a4.x + m4.y * a4.y + m4.z * a4.z + m4.w * a4.w;
    __shared__ float red[256];
    red[tid] = p; __syncthreads();
    for (int s = 128; s > 0; s >>= 1) { if (tid < s) red[tid] += red[tid + s]; __syncthreads(); }
    if (tid == 0) expzs[l * KDIM + row] = expf(red[0]);
}

// ---------------- CSR build: count -> scan -> scatter ----------------
__global__ __launch_bounds__(256) void count_edges(
    const int* __restrict__ dir_dst, const int* __restrict__ und_dst,
    const int* __restrict__ ek_dst, int* __restrict__ counts)
{
    int i = blockIdx.x * 256 + threadIdx.x;
    if (i < E_DIRN) atomicAdd(&counts[dir_dst[i]], 1);
    else if (i < E_DIRN + E_UNDN) atomicAdd(&counts[1024 + und_dst[i - E_DIRN]], 1);
    else if (i < TOT_E) atomicAdd(&counts[2048 + ek_dst[i - E_DIRN - E_UNDN]], 1);
}

__global__ __launch_bounds__(1024) void scan_bins(
    const int* __restrict__ counts, int* __restrict__ offsets)
{
    __shared__ int sums[1024];
    int tid = threadIdx.x;
    const int C = (NB + 1023) / 1024;  // 32
    int base = tid * C;
    int s = 0;
    for (int j = 0; j < C; ++j) { int idx = base + j; if (idx < NB) s += counts[idx]; }
    sums[tid] = s; __syncthreads();
    for (int off = 1; off < 1024; off <<= 1) {
        int v = (tid >= off) ? sums[tid - off] : 0;
        __syncthreads();
        sums[tid] += v;
        __syncthreads();
    }
    int run = (tid == 0) ? 0 : sums[tid - 1];
    for (int j = 0; j < C; ++j) {
        int idx = base + j;
        if (idx < NB) { offsets[idx] = run; run += counts[idx]; }
    }
}

__global__ __launch_bounds__(256) void scatter_edges(
    const int* __restrict__ dir_dst, const int* __restrict__ und_dst,
    const int* __restrict__ ek_dst, const int* __restrict__ offsets,
    int* __restrict__ cursor, int* __restrict__ edge_idx)
{
    int i = blockIdx.x * 256 + threadIdx.x;
    int bin, loc;
    if (i < E_DIRN) { bin = dir_dst[i]; loc = i; }
    else if (i < E_DIRN + E_UNDN) { loc = i - E_DIRN; bin = 1024 + und_dst[loc]; }
    else if (i < TOT_E) { loc = i - E_DIRN - E_UNDN; bin = 2048 + ek_dst[loc]; }
    else return;
    int pos = offsets[bin] + atomicAdd(&cursor[bin], 1);
    edge_idx[pos] = loc;
}

// ---------------- k_directed / k_undirected rows (single pass, batched gather) -------
__global__ __launch_bounds__(256) void gat_kn(
    const float* __restrict__ Zall, const float* __restrict__ expzs,
    const int* __restrict__ dir_src, const int* __restrict__ und_src,
    const int* __restrict__ offsets, const int* __restrict__ counts,
    const int* __restrict__ edge_idx,
    float* __restrict__ Bk, float* __restrict__ Ck)
{
    int bin = blockIdx.x;
    int g = bin >> 10, row = bin & 1023;
    const int* srcA = g ? und_src : dir_src;
    const float* Z = Zall + (size_t)g * KDIM * KDIM;
    const float* ez = expzs + g * KDIM;
    float* out = g ? Ck : Bk;
    int tid = threadIdx.x;
    int start = offsets[bin], n = counts[bin];
    __shared__ int   srcs[256];
    __shared__ float wsh[256];
    float4 acc = make_float4(0.f, 0.f, 0.f, 0.f);
    float den = 0.f;
    for (int c0 = 0; c0 < n; c0 += 256) {
        int m = min(256, n - c0);
        if (tid < m) {
            int e = edge_idx[start + c0 + tid];
            int s = srcA[e];
            srcs[tid] = s;
            wsh[tid] = ez[s];
        }
        __syncthreads();
        int j = 0;
        for (; j + 4 <= m; j += 4) {
            int s0 = srcs[j], s1 = srcs[j + 1], s2 = srcs[j + 2], s3 = srcs[j + 3];
            float w0 = wsh[j], w1 = wsh[j + 1], w2 = wsh[j + 2], w3 = wsh[j + 3];
            float4 z0 = *(const float4*)&Z[(size_t)s0 * KDIM + tid * 4];
            float4 z1 = *(const float4*)&Z[(size_t)s1 * KDIM + tid * 4];
            float4 z2 = *(const float4*)&Z[(size_t)s2 * KDIM + tid * 4];
            float4 z3 = *(const float4*)&Z[(size_t)s3 * KDIM + tid * 4];
            acc.x += w0 * z0.x + w1 * z1.x + w2 * z2.x + w3 * z3.x;
            acc.y += w0 * z0.y + w1 * z1.y + w2 * z2.y + w3 * z3.y;
            acc.z += w0 * z0.z + w1 * z1.z + w2 * z2.z + w3 * z3.z;
            acc.w += w0 * z0.w + w1 * z1.w + w2 * z2.w + w3 * z3.w;
            den += w0 + w1 + w2 + w3;
        }
        for (; j < m; ++j) {
            int s = srcs[j]; float w = wsh[j];
            float4 z4 = *(const float4*)&Z[(size_t)s * KDIM + tid * 4];
            acc.x += w * z4.x; acc.y += w * z4.y; acc.z += w * z4.z; acc.w += w * z4.w;
            den += w;
        }
        __syncthreads();
    }
    float inv = (n > 0) ? 1.f / den : 0.f;
    acc.x *= inv; acc.y *= inv; acc.z *= inv; acc.w *= inv;
    *(float4*)&out[(size_t)row * KDIM + tid * 4] = acc;
}

// ---------------- exer_out rows (single pass, batched gather, fused epilogue) --------
__global__ __launch_bounds__(256) void exer_rows(
    const float* __restrict__ exer, const float* __restrict__ Zek,
    const float* __restrict__ expzs_ek, const int* __restrict__ ek_src,
    const int* __restrict__ offsets, const int* __restrict__ counts,
    const int* __restrict__ edge_idx,
    const float* __restrict__ e_w1, const float* __restrict__ e_b1,
    float* __restrict__ out)
{
    int row = blockIdx.x, tid = threadIdx.x;
    int bin = 2048 + row;
    int start = offsets[bin], n = counts[bin];
    __shared__ int   srcs[64];
    __shared__ float wsh[64];
    __shared__ float red[256];
    float4 x4 = *(const float4*)&exer[(size_t)row * KDIM + tid * 4];
    float4 be = make_float4(0.f, 0.f, 0.f, 0.f);
    float den = 0.f;
    for (int c0 = 0; c0 < n; c0 += 64) {
        int m = min(64, n - c0);
        if (tid < m) {
            int e = edge_idx[start + c0 + tid];
            int s = ek_src[e] - E_N;
            srcs[tid] = s;
            wsh[tid] = expzs_ek[s];
        }
        __syncthreads();
        int j = 0;
        for (; j + 4 <= m; j += 4) {
            int s0 = srcs[j], s1 = srcs[j + 1], s2 = srcs[j + 2], s3 = srcs[j + 3];
            float w0 = wsh[j], w1 = wsh[j + 1], w2 = wsh[j + 2], w3 = wsh[j + 3];
            float4 z0 = *(const float4*)&Zek[(size_t)s0 * KDIM + tid * 4];
            float4 z1 = *(const float4*)&Zek[(size_t)s1 * KDIM + tid * 4];
            float4 z2 = *(const float4*)&Zek[(size_t)s2 * KDIM + tid * 4];
            float4 z3 = *(const float4*)&Zek[(size_t)s3 * KDIM + tid * 4];
            be.x += w0 * z0.x + w1 * z1.x + w2 * z2.x + w3 * z3.x;
            be.y += w0 * z0.y + w1 * z1.y + w2 * z2.y + w3 * z3.y;
            be.z += w0 * z0.z + w1 * z1.z + w2 * z2.z + w3 * z3.z;
            be.w += w0 * z0.w + w1 * z1.w + w2 * z2.w + w3 * z3.w;
            den += w0 + w1 + w2 + w3;
        }
        for (; j < m; ++j) {
            int s = srcs[j]; float w = wsh[j];
            float4 z4 = *(const float4*)&Zek[(size_t)s * KDIM + tid * 4];
            be.x += w * z4.x; be.y += w * z4.y; be.z += w * z4.z; be.w += w * z4.w;
            den += w;
        }
        __syncthreads();
    }
    float inv = (n > 0) ? 1.f / den : 0.f;
    be.x *= inv; be.y *= inv; be.z *= inv; be.w *= inv;
    float4 wa = *(const float4*)&e_w1[tid * 4];
    float4 wb = *(const float4*)&e_w1[KDIM + tid * 4];
    float p = x4.x * wa.x + x4.y * wa.y + x4.z * wa.z + x4.w * wa.w
            + be.x * wb.x + be.y * wb.y + be.z * wb.z + be.w * wb.w;
    red[tid] = p; __syncthreads();
    for (int s = 128; s > 0; s >>= 1) { if (tid < s) red[tid] += red[tid + s]; __syncthreads(); }
    float se = red[0] + e_b1[0];
    float4 o;
    o.x = x4.x + se * be.x; o.y = x4.y + se * be.y;
    o.z = x4.z + se * be.z; o.w = x4.w + se * be.w;
    *(float4*)&out[(size_t)row * KDIM + tid * 4] = o;
}

// ---------------- kn_out rows: 2-way gated combine ----------------
__global__ __launch_bounds__(256) void kn_rows(
    const float* __restrict__ A, const float* __restrict__ Bk, const float* __restrict__ Ck,
    const float* __restrict__ k_w1, const float* __restrict__ k_b1,
    const float* __restrict__ k_w2, const float* __restrict__ k_b2,
    float* __restrict__ out)
{
    int row = blockIdx.x, tid = threadIdx.x;
    float4 a4 = *(const float4*)&A[(size_t)row * KDIM + tid * 4];
    float4 b4 = *(const float4*)&Bk[(size_t)row * KDIM + tid * 4];
    float4 c4 = *(const float4*)&Ck[(size_t)row * KDIM + tid * 4];
    float4 w1a = *(const float4*)&k_w1[tid * 4];
    float4 w1b = *(const float4*)&k_w1[KDIM + tid * 4];
    float4 w2a = *(const float4*)&k_w2[tid * 4];
    float4 w2b = *(const float4*)&k_w2[KDIM + tid * 4];
    float p1 = a4.x * w1a.x + a4.y * w1a.y + a4.z * w1a.z + a4.w * w1a.w
             + b4.x * w1b.x + b4.y * w1b.y + b4.z * w1b.z + b4.w * w1b.w;
    float p2 = a4.x * w2a.x + a4.y * w2a.y + a4.z * w2a.z + a4.w * w2a.w
             + c4.x * w2b.x + c4.y * w2b.y + c4.z * w2b.z + c4.w * w2b.w;
    __shared__ float r1[256];
    __shared__ float r2[256];
    r1[tid] = p1; r2[tid] = p2; __syncthreads();
    for (int s = 128; s > 0; s >>= 1) {
        if (tid < s) { r1[tid] += r1[tid + s]; r2[tid] += r2[tid + s]; }
        __syncthreads();
    }
    float s1 = r1[0] + k_b1[0];
    float s2 = r2[0] + k_b2[0];
    float m = fmaxf(s1, s2);
    float e1 = expf(s1 - m), e2 = expf(s2 - m);
    float isum = 1.f / (e1 + e2);
    float sc0 = e1 * isum, sc1 = e2 * isum;
    float4 o;
    o.x = a4.x + sc0 * b4.x + sc1 * c4.x;
    o.y = a4.y + sc0 * b4.y + sc1 * c4.y;
    o.z = a4.z + sc0 * b4.z + sc1 * c4.z;
    o.w = a4.w + sc0 * b4.w + sc1 * c4.w;
    *(float4*)&out[(size_t)row * KDIM + tid * 4] = o;
}

extern "C" void kernel_launch(void* const* d_in, const int* in_sizes, int n_in,
                              void* d_out, int out_size, void* d_ws, size_t ws_size,
                              hipStream_t stream)
{
    (void)in_sizes; (void)n_in; (void)out_size; (void)ws_size;
    const float* exer  = (const float*)d_in[0];
    const float* kn    = (const float*)d_in[1];
    const int* dir_src = (const int*)d_in[2];
    const int* dir_dst = (const int*)d_in[3];
    const int* und_src = (const int*)d_in[4];
    const int* und_dst = (const int*)d_in[5];
    const int* ek_src  = (const int*)d_in[6];
    const int* ek_dst  = (const int*)d_in[7];
    const float* W_dir = (const float*)d_in[8];
    const float* a_dir = (const float*)d_in[9];
    const float* W_und = (const float*)d_in[10];
    const float* a_und = (const float*)d_in[11];
    const float* W_ek  = (const float*)d_in[12];
    const float* a_ek  = (const float*)d_in[13];
    const float* k_w1  = (const float*)d_in[14];
    const float* k_b1  = (const float*)d_in[15];
    const float* k_w2  = (const float*)d_in[16];
    const float* k_b2  = (const float*)d_in[17];
    const float* e_w1  = (const float*)d_in[18];
    const float* e_b1  = (const float*)d_in[19];

    char* ws = (char*)d_ws;
    float* Zall    = (float*)ws; ws += (size_t)3 * KDIM * KDIM * 4;
    float* Bk      = (float*)ws; ws += (size_t)KDIM * KDIM * 4;
    float* Ck      = (float*)ws; ws += (size_t)KDIM * KDIM * 4;
    float* expzs   = (float*)ws; ws += 3 * KDIM * 4;
    int* counts    = (int*)ws;   ws += NB * 4;
    int* cursor    = (int*)ws;   ws += NB * 4;   // contiguous with counts: one memset
    int* offsets   = (int*)ws;   ws += NB * 4;
    int* edge_idx  = (int*)ws;   ws += (size_t)TOT_E * 4;
    unsigned short* knb = (unsigned short*)ws; ws += (size_t)KDIM * KDIM * 2;
    unsigned short* Wtb = (unsigned short*)ws; ws += (size_t)3 * KDIM * KDIM * 2;

    hipMemsetAsync(counts, 0, (size_t)2 * NB * 4, stream);

    convert_kn<<<KDIM * KDIM / 8 / 256, 256, 0, stream>>>(kn, knb);
    transpose_w<<<dim3(32, 32, 3), dim3(32, 8), 0, stream>>>(W_dir, W_und, W_ek, Wtb);
    gemm_mfma<<<dim3(8, 8, 3), 256, 0, stream>>>(knb, Wtb, Zall);
    rowdot_exp<<<dim3(KDIM, 3), 256, 0, stream>>>(Zall, a_dir, a_und, a_ek, expzs);

    int eb = (TOT_E + 255) / 256;
    count_edges<<<eb, 256, 0, stream>>>(dir_dst, und_dst, ek_dst, counts);
    scan_bins<<<1, 1024, 0, stream>>>(counts, offsets);
    scatter_edges<<<eb, 256, 0, stream>>>(dir_dst, und_dst, ek_dst, offsets, cursor, edge_idx);

    gat_kn<<<2048, 256, 0, stream>>>(Zall, expzs, dir_src, und_src, offsets, counts, edge_idx, Bk, Ck);

    float* out = (float*)d_out;
    exer_rows<<<E_N, 256, 0, stream>>>(exer, Zall + (size_t)2 * KDIM * KDIM, expzs + 2 * KDIM,
                                       ek_src, offsets, counts, edge_idx, e_w1, e_b1, out);
    kn_rows<<<KDIM, 256, 0, stream>>>(kn, Bk, Ck, k_w1, k_b1, k_w2, k_b2,
                                      out + (size_t)E_N * KDIM);
}